// Round 10
// baseline (13772.455 us; speedup 1.0000x reference)
//
#include <hip/hip_runtime.h>
#include <hip/hip_bf16.h>

// Problem dims
#define TT    2048
#define DD    1024
#define HH    2048
#define TAGS_ 1024
#define G4    8192   // 4*H

typedef float f32x4 __attribute__((ext_vector_type(4)));
typedef __bf16 bf16x8 __attribute__((ext_vector_type(8)));
typedef _Float16 f16x2 __attribute__((ext_vector_type(2)));
typedef _Float16 f16x4 __attribute__((ext_vector_type(4)));
typedef unsigned u32x2 __attribute__((ext_vector_type(2)));

__device__ __forceinline__ unsigned short f2bf(float f) {
    unsigned u = __float_as_uint(f);
    unsigned r = (u + 0x7fffu + ((u >> 16) & 1u)) >> 16;
    return (unsigned short)r;
}

__device__ __forceinline__ f16x2 u2h(unsigned u) {
    return __builtin_bit_cast(f16x2, u);
}

#if __has_builtin(__builtin_amdgcn_fdot2)
#define FDOT2(a, b, c) __builtin_amdgcn_fdot2((a), (b), (c), false)
#else
__device__ __forceinline__ float FDOT2(f16x2 a, f16x2 b, float c) {
    return fmaf((float)a.x, (float)b.x, fmaf((float)a.y, (float)b.y, c));
}
#endif

// full-wave (64-lane) sum via DPP ladder; result broadcast via readlane 63
__device__ __forceinline__ float dpp_sum64(float x) {
    int t;
    t = __builtin_amdgcn_update_dpp(0, __float_as_int(x), 0x111, 0xf, 0xf, true); // row_shr:1
    x += __int_as_float(t);
    t = __builtin_amdgcn_update_dpp(0, __float_as_int(x), 0x112, 0xf, 0xf, true); // row_shr:2
    x += __int_as_float(t);
    t = __builtin_amdgcn_update_dpp(0, __float_as_int(x), 0x114, 0xf, 0xf, true); // row_shr:4
    x += __int_as_float(t);
    t = __builtin_amdgcn_update_dpp(0, __float_as_int(x), 0x118, 0xf, 0xf, true); // row_shr:8
    x += __int_as_float(t);
    t = __builtin_amdgcn_update_dpp(0, __float_as_int(x), 0x142, 0xa, 0xf, true); // row_bcast:15
    x += __int_as_float(t);
    t = __builtin_amdgcn_update_dpp(0, __float_as_int(x), 0x143, 0xc, 0xf, true); // row_bcast:31
    x += __int_as_float(t);
    return __int_as_float(__builtin_amdgcn_readlane(__float_as_int(x), 63));
}

// ---------------- fp32 -> bf16 convert ----------------
__global__ __launch_bounds__(256) void cvt_bf16_k(const float* __restrict__ in,
                                                  unsigned short* __restrict__ out, int n) {
    int i = (blockIdx.x * 256 + threadIdx.x) * 4;
    if (i < n) {
        float4 v = *(const float4*)(in + i);
        ushort4 o;
        o.x = f2bf(v.x); o.y = f2bf(v.y); o.z = f2bf(v.z); o.w = f2bf(v.w);
        *(ushort4*)(out + i) = o;
    }
}

// ---------------- fp32 -> fp16 convert ----------------
__global__ __launch_bounds__(256) void cvt_f16_k(const float* __restrict__ in,
                                                 _Float16* __restrict__ out, int n) {
    int i = (blockIdx.x * 256 + threadIdx.x) * 4;
    if (i < n) {
        float4 v = *(const float4*)(in + i);
        f16x4 o;
        o.x = (_Float16)v.x; o.y = (_Float16)v.y;
        o.z = (_Float16)v.z; o.w = (_Float16)v.w;
        *(f16x4*)(out + i) = o;
    }
}

// ------------- tagged word (f16 in low16) -> bf16 -------------
__global__ __launch_bounds__(256) void cvt_lo16f_k(const unsigned* __restrict__ in,
                                                   unsigned short* __restrict__ out, int n) {
    int i = (blockIdx.x * 256 + threadIdx.x) * 4;
    if (i < n) {
        uint4 v = *(const uint4*)(in + i);
        ushort4 o;
        o.x = f2bf((float)__builtin_bit_cast(_Float16, (unsigned short)(v.x & 0xffff)));
        o.y = f2bf((float)__builtin_bit_cast(_Float16, (unsigned short)(v.y & 0xffff)));
        o.z = f2bf((float)__builtin_bit_cast(_Float16, (unsigned short)(v.z & 0xffff)));
        o.w = f2bf((float)__builtin_bit_cast(_Float16, (unsigned short)(v.w & 0xffff)));
        *(ushort4*)(out + i) = o;
    }
}

// ---------------- bf16 MFMA GEMM: C[M][N] = A[M][K] * B[N][K]^T + bias ----------------
__global__ __launch_bounds__(256) void gemm_bt_k(const unsigned short* __restrict__ A,
                                                 const unsigned short* __restrict__ B,
                                                 void* __restrict__ Cv,
                                                 const float* __restrict__ bias1,
                                                 const float* __restrict__ bias2,
                                                 int M, int N, int K, int out_f16) {
    const int bn = blockIdx.x, bm = blockIdx.y;
    const int tid = threadIdx.x;
    const int wave = tid >> 6, lane = tid & 63;
    const int wm = (wave >> 1) * 64, wn = (wave & 1) * 64;

    __shared__ unsigned short As[128 * 64];
    __shared__ unsigned short Bs[128 * 64];

    f32x4 acc[4][4] = {};

    for (int k0 = 0; k0 < K; k0 += 64) {
#pragma unroll
        for (int i = 0; i < 4; ++i) {
            int bo = (tid + i * 256) * 16;
            int r = bo >> 7;
            int cb = bo & 127;
            *(uint4*)((char*)As + bo) =
                *(const uint4*)((const char*)(A + (size_t)(bm * 128 + r) * K + k0) + cb);
            *(uint4*)((char*)Bs + bo) =
                *(const uint4*)((const char*)(B + (size_t)(bn * 128 + r) * K + k0) + cb);
        }
        __syncthreads();
#pragma unroll
        for (int kk = 0; kk < 64; kk += 32) {
            int kb = kk + (lane >> 4) * 8;
            bf16x8 af[4], bfr[4];
#pragma unroll
            for (int mi = 0; mi < 4; ++mi)
                af[mi] = *(const bf16x8*)&As[(wm + mi * 16 + (lane & 15)) * 64 + kb];
#pragma unroll
            for (int ni = 0; ni < 4; ++ni)
                bfr[ni] = *(const bf16x8*)&Bs[(wn + ni * 16 + (lane & 15)) * 64 + kb];
#pragma unroll
            for (int mi = 0; mi < 4; ++mi)
#pragma unroll
                for (int ni = 0; ni < 4; ++ni)
                    acc[mi][ni] = __builtin_amdgcn_mfma_f32_16x16x32_bf16(
                        af[mi], bfr[ni], acc[mi][ni], 0, 0, 0);
        }
        __syncthreads();
    }

#pragma unroll
    for (int ni = 0; ni < 4; ++ni) {
        int col = bn * 128 + wn + ni * 16 + (lane & 15);
        float bv = bias1 ? bias1[col] : 0.0f;
        if (bias2) bv += bias2[col];
#pragma unroll
        for (int mi = 0; mi < 4; ++mi) {
            int row = bm * 128 + wm + mi * 16 + (lane >> 4) * 4;
#pragma unroll
            for (int r = 0; r < 4; ++r) {
                float v = acc[mi][ni][r] + bv;
                if (out_f16)
                    ((_Float16*)Cv)[(size_t)(row + r) * N + col] = (_Float16)v;
                else
                    ((float*)Cv)[(size_t)(row + r) * N + col] = v;
            }
        }
    }
}

// ---------------- persistent recurrent kernel ----------------
// 256 WGs x 512 threads, 1 WG/CU. Wave w of WG b owns hidden unit b*8+w.
// W_hh fp16 pinned in AGPRs. Sync: tagged words hs32[t][u]=(t<<16)|f16(h).
// Consumer poll: 2-deep counted rotation (vmcnt(1) retires oldest; publish
// store is older so it retires first), sched_barrier(0) after every wait
// (check cannot hoist past the waitcnt), s_sleep(1) per full miss round
// (R9 lesson: hot polling saturates LLC). Exit drains vmcnt(0) and dummy-
// uses all poll dwords so no in-flight load lands in a reassigned register
// (R7 crash fix). xg via s_load issued at step top, waited only after the
// dot/reduce phase (R9 lesson: immediate lgkm wait serializes xg latency).
__global__ __launch_bounds__(512, 2) void lstm_rec_k(const _Float16* __restrict__ Whh16,
                                                     const _Float16* __restrict__ xg,
                                                     unsigned* __restrict__ hs32) {
    const int tid = threadIdx.x;
    const int wave = tid >> 6;
    const int lane = tid & 63;
    const int unit = (blockIdx.x << 3) + wave;   // hidden unit owned by this wave

    __shared__ unsigned hpk[2][1024];            // packed f16 pairs of h_t (ping-pong)

    // weights: W[g][k][p] = dword p of Whh16[g*H + unit][k*256 + lane*4 ..+3]
    unsigned W[4][8][2];
#pragma unroll
    for (int g = 0; g < 4; ++g) {
        const _Float16* wr = Whh16 + ((size_t)(g * HH) + unit) * HH + (lane << 2);
#pragma unroll
        for (int k = 0; k < 8; ++k) {
            u32x2 v = *(const u32x2*)(wr + (k << 8));
            W[g][k][0] = v.x; W[g][k][1] = v.y;
        }
    }
#pragma unroll
    for (int g = 0; g < 4; ++g)
#pragma unroll
        for (int k = 0; k < 8; ++k)
            asm volatile("" : "+a"(W[g][k][0]), "+a"(W[g][k][1]));

    float creg = 0.0f;

    // wave-uniform scalar-load base for xg (dword aligned) and half-select
    const unsigned sh = (unit & 1) << 4;
    unsigned long long xbase = (unsigned long long)(uintptr_t)xg + ((unsigned)(unit << 1) & ~3u);

#define ISSUE(r)                                                              \
    asm volatile("global_load_dwordx4 %0, %1, off sc0 sc1"                    \
                 : "=&v"(r) : "v"(pp))
#define CHECK(r)                                                              \
    __all((int)(((r.x >> 16) == tu) & ((r.y >> 16) == tu) &                   \
                ((r.z >> 16) == tu) & ((r.w >> 16) == tu)))

    for (int t = 0; t < TT; ++t) {
        const int buf = t & 1;
        const unsigned tu = (unsigned)t;
        const unsigned* pp = hs32 + ((size_t)t << 11) + (wave << 8) + (lane << 2);

        // 1. issue 2-deep poll pipeline
        uint4 r0, r1;
        ISSUE(r0);
        ISSUE(r1);

        // 2. issue xg scalar loads (SMEM -> lgkm, not vmcnt; NO wait here --
        //    latency hides under poll + dots; consumed after the reduce)
        unsigned sd0, sd1, sd2, sd3;
        {
            unsigned long long xaddr = xbase + ((unsigned long long)t << 14);
            unsigned alo = __builtin_amdgcn_readfirstlane((unsigned)xaddr);
            unsigned ahi = __builtin_amdgcn_readfirstlane((unsigned)(xaddr >> 32));
            unsigned long long ua = ((unsigned long long)ahi << 32) | alo;
            asm volatile(
                "s_load_dword %0, %4, 0x0\n\t"
                "s_load_dword %1, %4, 0x1000\n\t"
                "s_load_dword %2, %4, 0x2000\n\t"
                "s_load_dword %3, %4, 0x3000"
                : "=s"(sd0), "=s"(sd1), "=s"(sd2), "=s"(sd3)
                : "s"(ua));
        }

        // 3. rotating 2-deep poll: vmcnt(1) retires the oldest (publish store
        //    first, then the oldest poll); sched_barrier pins the check after
        //    the wait; sleep once per full miss round
        uint4 hv;
        for (;;) {
            asm volatile("s_waitcnt vmcnt(1)" ::: "memory");
            __builtin_amdgcn_sched_barrier(0);
            if (CHECK(r0)) { hv = r0; break; }
            ISSUE(r0);
            asm volatile("s_waitcnt vmcnt(1)" ::: "memory");
            __builtin_amdgcn_sched_barrier(0);
            if (CHECK(r1)) { hv = r1; break; }
            ISSUE(r1);
            __builtin_amdgcn_s_sleep(1);
        }
        // 4. drain in-flight poll; dummy-use keeps r0/r1 registers live so
        //    the landing load cannot clobber a reassigned register
        asm volatile("s_waitcnt vmcnt(0)" ::: "memory");
        asm volatile("" :: "v"(r0.x), "v"(r0.y), "v"(r0.z), "v"(r0.w),
                           "v"(r1.x), "v"(r1.y), "v"(r1.z), "v"(r1.w));
        __builtin_amdgcn_sched_barrier(0);

        // 5. pack + stage own slice to LDS ping-pong, barrier
        unsigned plo = __builtin_amdgcn_perm(hv.y, hv.x, 0x05040100);
        unsigned phi = __builtin_amdgcn_perm(hv.w, hv.z, 0x05040100);
        {
            u32x2 pk; pk.x = plo; pk.y = phi;
            *(u32x2*)&hpk[buf][(wave << 7) + (lane << 1)] = pk;
        }
        __syncthreads();

        // 6. dots over 8 slices (own slice from regs)
        float a0 = 0.f, a1 = 0.f, a2 = 0.f, a3 = 0.f;
#define DOTS(kk, PLO, PHI) do {                                               \
        f16x2 hlo = u2h(PLO), hhi = u2h(PHI);                                 \
        a0 = FDOT2(u2h(W[0][kk][0]), hlo, a0);                                \
        a0 = FDOT2(u2h(W[0][kk][1]), hhi, a0);                                \
        a1 = FDOT2(u2h(W[1][kk][0]), hlo, a1);                                \
        a1 = FDOT2(u2h(W[1][kk][1]), hhi, a1);                                \
        a2 = FDOT2(u2h(W[2][kk][0]), hlo, a2);                                \
        a2 = FDOT2(u2h(W[2][kk][1]), hhi, a2);                                \
        a3 = FDOT2(u2h(W[3][kk][0]), hlo, a3);                                \
        a3 = FDOT2(u2h(W[3][kk][1]), hhi, a3);                                \
    } while (0)
#define SLICE(kk) do {                                                        \
        if ((kk) == wave) {                                                   \
            DOTS(kk, plo, phi);                                               \
        } else {                                                              \
            u32x2 hp = *(const u32x2*)&hpk[buf][((kk) << 7) + (lane << 1)];   \
            DOTS(kk, hp.x, hp.y);                                             \
        }                                                                     \
    } while (0)
        SLICE(0); SLICE(1); SLICE(2); SLICE(3);
        SLICE(4); SLICE(5); SLICE(6); SLICE(7);
#undef SLICE
#undef DOTS

        // 7. wave reduce (DPP ladder) -> uniform sums
        float s0 = dpp_sum64(a0);
        float s1 = dpp_sum64(a1);
        float s2 = dpp_sum64(a2);
        float s3 = dpp_sum64(a3);

        // 8. consume xg s_loads now (latency long hidden); fence the use
        asm volatile("s_waitcnt lgkmcnt(0)" ::: "memory");
        __builtin_amdgcn_sched_barrier(0);
        float xv0 = (float)__builtin_bit_cast(_Float16, (unsigned short)((sd0 >> sh) & 0xffffu));
        float xv1 = (float)__builtin_bit_cast(_Float16, (unsigned short)((sd1 >> sh) & 0xffffu));
        float xv2 = (float)__builtin_bit_cast(_Float16, (unsigned short)((sd2 >> sh) & 0xffffu));
        float xv3 = (float)__builtin_bit_cast(_Float16, (unsigned short)((sd3 >> sh) & 0xffffu));

        float gi = s0 + xv0;
        float gf = s1 + xv1;
        float gg = s2 + xv2;
        float go = s3 + xv3;

        // 9. activation (uniform across all lanes; no divergence)
        float ei = __expf(-gi), ef = __expf(-gf), eo = __expf(-go);
        float eg = __expf(-2.0f * gg);
        float si = 1.0f / (1.0f + ei);
        float sf = 1.0f / (1.0f + ef);
        float so = 1.0f / (1.0f + eo);
        float tg = 2.0f / (1.0f + eg) - 1.0f;
        creg = sf * creg + si * tg;
        float ec = __expf(-2.0f * creg);
        float th = 2.0f / (1.0f + ec) - 1.0f;
        float h = so * th;
        _Float16 fh = (_Float16)h;
        unsigned word = ((tu + 1u) << 16) |
                        (unsigned)__builtin_bit_cast(unsigned short, fh);

        // 10. publish (fire-and-forget; retired by next step's vmcnt waits)
        if (lane == 0) {
            unsigned* hd = hs32 + (((size_t)(t + 1)) << 11) + unit;
            asm volatile("global_store_dword %0, %1, off sc0 sc1"
                         :: "v"(hd), "v"(word));
        }
    }
#undef ISSUE
#undef CHECK
}

// ---------------- log-softmax over rows of [T][TAGS] ----------------
__global__ __launch_bounds__(256) void lsm_k(const float* __restrict__ tag,
                                             float* __restrict__ out) {
    const int row = blockIdx.x, tid = threadIdx.x;
    const int wave = tid >> 6, lane = tid & 63;
    const float* p = tag + ((size_t)row << 10);
    float v0 = p[tid], v1 = p[tid + 256], v2 = p[tid + 512], v3 = p[tid + 768];
    float m = fmaxf(fmaxf(v0, v1), fmaxf(v2, v3));
#pragma unroll
    for (int off = 32; off >= 1; off >>= 1) m = fmaxf(m, __shfl_xor(m, off, 64));
    __shared__ float redm[4];
    __shared__ float reds[4];
    if (lane == 0) redm[wave] = m;
    __syncthreads();
    m = fmaxf(fmaxf(redm[0], redm[1]), fmaxf(redm[2], redm[3]));
    float s = __expf(v0 - m) + __expf(v1 - m) + __expf(v2 - m) + __expf(v3 - m);
#pragma unroll
    for (int off = 32; off >= 1; off >>= 1) s += __shfl_xor(s, off, 64);
    if (lane == 0) reds[wave] = s;
    __syncthreads();
    s = reds[0] + reds[1] + reds[2] + reds[3];
    float lse = m + __logf(s);
    float* o = out + ((size_t)row << 10);
    o[tid] = v0 - lse; o[tid + 256] = v1 - lse;
    o[tid + 512] = v2 - lse; o[tid + 768] = v3 - lse;
}

extern "C" void kernel_launch(void* const* d_in, const int* in_sizes, int n_in,
                              void* d_out, int out_size, void* d_ws, size_t ws_size,
                              hipStream_t stream) {
    const float* x    = (const float*)d_in[0];
    const float* Wih  = (const float*)d_in[1];
    const float* Whh  = (const float*)d_in[2];
    const float* bih  = (const float*)d_in[3];
    const float* bhh  = (const float*)d_in[4];
    const float* Wout = (const float*)d_in[5];
    const float* bout = (const float*)d_in[6];
    float* out = (float*)d_out;

    // workspace carve with time-sliced aliasing (all uses stream-ordered):
    //  A: hs32 [16.8MB] tagged h words; aliased by `tag` in phase C
    //  B: xg   [32MB]   f16 gate preacts
    //  C: 33.6MB region:
    //     pre-GEMM-A: xbf @C+0 (4MB), wihbf @C+4MB (16MB)
    //     pre-rec   : Whh16 @C+0 (33.6MB)   [cvt AFTER phase A]
    //     post-rec  : woutbf @C+0 (4MB), hs bf16 @C+4MB (8MB)
    char* ws = (char*)d_ws;
    size_t off = 0;
    unsigned* hs32 = (unsigned*)(ws + off); off += (size_t)(TT + 1) * HH * 4;   // 16.8MB
    float* tag = (float*)hs32;                                                   // alias
    _Float16* xg = (_Float16*)(ws + off); off += (size_t)TT * G4 * 2;            // 32MB
    char* C = ws + off; off += (size_t)G4 * HH * 2;                              // 33.6MB
    unsigned short* xbf    = (unsigned short*)(C);
    unsigned short* wihbf  = (unsigned short*)(C + ((size_t)TT * DD * 2) * 2);   // C+4MB
    _Float16* Whh16        = (_Float16*)(C);
    unsigned short* woutbf = (unsigned short*)(C);
    unsigned short* hs     = (unsigned short*)(C + (size_t)4 * 1024 * 1024);     // C+4MB

    // clear ALL tags every call (h_0 = tag 0 + f16 zero; also prevents timed
    // replays from observing stale tags)
    hipMemsetAsync(hs32, 0, (size_t)(TT + 1) * HH * 4, stream);

    // converts for phase A
    cvt_bf16_k<<<(TT * DD) / 1024, 256, 0, stream>>>(x, xbf, TT * DD);
    cvt_bf16_k<<<(G4 * DD) / 1024, 256, 0, stream>>>(Wih, wihbf, G4 * DD);

    // phase A: xg[T][4H] (f16) = x @ W_ih^T + (b_ih + b_hh)
    gemm_bt_k<<<dim3(G4 / 128, TT / 128), 256, 0, stream>>>(xbf, wihbf, (void*)xg,
                                                            bih, bhh, TT, G4, DD, 1);

    // W_hh -> f16 (overwrites xbf/wihbf region — phase A is done with them)
    cvt_f16_k<<<(G4 * HH) / 1024, 256, 0, stream>>>(Whh, Whh16, G4 * HH);

    // phase B: recurrence (persistent dataflow kernel, 1 WG/CU)
    {
        const _Float16* whh_p = Whh16;
        const _Float16* xg_p = xg;
        unsigned* hs32_p = hs32;
        void* args[] = {(void*)&whh_p, (void*)&xg_p, (void*)&hs32_p};
        hipLaunchCooperativeKernel((const void*)lstm_rec_k, dim3(256), dim3(512), args, 0,
                                   stream);
    }

    // converts for phase C (overwrite Whh16 region — recurrence is done)
    cvt_bf16_k<<<(TAGS_ * HH) / 1024, 256, 0, stream>>>(Wout, woutbf, TAGS_ * HH);
    cvt_lo16f_k<<<(TT * HH) / 1024, 256, 0, stream>>>(hs32 + HH, hs, TT * HH);

    // phase C: tag[T][TAGS] = hs @ W_out^T + b_out  (tag aliases hs32; the
    // post-pass above already consumed hs32)
    gemm_bt_k<<<dim3(TAGS_ / 128, TT / 128), 256, 0, stream>>>(hs, woutbf, (void*)tag,
                                                               bout, nullptr,
                                                               TT, TAGS_, HH, 0);

    // log-softmax
    lsm_k<<<TT, 256, 0, stream>>>(tag, out);
}

// Round 11
// 7826.952 us; speedup vs baseline: 1.7596x; 1.7596x over previous
//
#include <hip/hip_runtime.h>
#include <hip/hip_bf16.h>

// Problem dims
#define TT    2048
#define DD    1024
#define HH    2048
#define TAGS_ 1024
#define G4    8192   // 4*H

typedef float f32x4 __attribute__((ext_vector_type(4)));
typedef __bf16 bf16x8 __attribute__((ext_vector_type(8)));
typedef _Float16 f16x2 __attribute__((ext_vector_type(2)));
typedef _Float16 f16x4 __attribute__((ext_vector_type(4)));
typedef unsigned u32x2 __attribute__((ext_vector_type(2)));

__device__ __forceinline__ unsigned short f2bf(float f) {
    unsigned u = __float_as_uint(f);
    unsigned r = (u + 0x7fffu + ((u >> 16) & 1u)) >> 16;
    return (unsigned short)r;
}

__device__ __forceinline__ f16x2 u2h(unsigned u) {
    return __builtin_bit_cast(f16x2, u);
}

#if __has_builtin(__builtin_amdgcn_fdot2)
#define FDOT2(a, b, c) __builtin_amdgcn_fdot2((a), (b), (c), false)
#else
__device__ __forceinline__ float FDOT2(f16x2 a, f16x2 b, float c) {
    return fmaf((float)a.x, (float)b.x, fmaf((float)a.y, (float)b.y, c));
}
#endif

// full-wave (64-lane) sum via DPP ladder; result broadcast via readlane 63
// (numerics validated in rounds 9/10: absmax unchanged vs shfl tree)
__device__ __forceinline__ float dpp_sum64(float x) {
    int t;
    t = __builtin_amdgcn_update_dpp(0, __float_as_int(x), 0x111, 0xf, 0xf, true); // row_shr:1
    x += __int_as_float(t);
    t = __builtin_amdgcn_update_dpp(0, __float_as_int(x), 0x112, 0xf, 0xf, true); // row_shr:2
    x += __int_as_float(t);
    t = __builtin_amdgcn_update_dpp(0, __float_as_int(x), 0x114, 0xf, 0xf, true); // row_shr:4
    x += __int_as_float(t);
    t = __builtin_amdgcn_update_dpp(0, __float_as_int(x), 0x118, 0xf, 0xf, true); // row_shr:8
    x += __int_as_float(t);
    t = __builtin_amdgcn_update_dpp(0, __float_as_int(x), 0x142, 0xa, 0xf, true); // row_bcast:15
    x += __int_as_float(t);
    t = __builtin_amdgcn_update_dpp(0, __float_as_int(x), 0x143, 0xc, 0xf, true); // row_bcast:31
    x += __int_as_float(t);
    return __int_as_float(__builtin_amdgcn_readlane(__float_as_int(x), 63));
}

// ---------------- fp32 -> bf16 convert ----------------
__global__ __launch_bounds__(256) void cvt_bf16_k(const float* __restrict__ in,
                                                  unsigned short* __restrict__ out, int n) {
    int i = (blockIdx.x * 256 + threadIdx.x) * 4;
    if (i < n) {
        float4 v = *(const float4*)(in + i);
        ushort4 o;
        o.x = f2bf(v.x); o.y = f2bf(v.y); o.z = f2bf(v.z); o.w = f2bf(v.w);
        *(ushort4*)(out + i) = o;
    }
}

// ---------------- fp32 -> fp16 convert ----------------
__global__ __launch_bounds__(256) void cvt_f16_k(const float* __restrict__ in,
                                                 _Float16* __restrict__ out, int n) {
    int i = (blockIdx.x * 256 + threadIdx.x) * 4;
    if (i < n) {
        float4 v = *(const float4*)(in + i);
        f16x4 o;
        o.x = (_Float16)v.x; o.y = (_Float16)v.y;
        o.z = (_Float16)v.z; o.w = (_Float16)v.w;
        *(f16x4*)(out + i) = o;
    }
}

// ------------- tagged word (f16 in low16) -> bf16 -------------
__global__ __launch_bounds__(256) void cvt_lo16f_k(const unsigned* __restrict__ in,
                                                   unsigned short* __restrict__ out, int n) {
    int i = (blockIdx.x * 256 + threadIdx.x) * 4;
    if (i < n) {
        uint4 v = *(const uint4*)(in + i);
        ushort4 o;
        o.x = f2bf((float)__builtin_bit_cast(_Float16, (unsigned short)(v.x & 0xffff)));
        o.y = f2bf((float)__builtin_bit_cast(_Float16, (unsigned short)(v.y & 0xffff)));
        o.z = f2bf((float)__builtin_bit_cast(_Float16, (unsigned short)(v.z & 0xffff)));
        o.w = f2bf((float)__builtin_bit_cast(_Float16, (unsigned short)(v.w & 0xffff)));
        *(ushort4*)(out + i) = o;
    }
}

// ---------------- bf16 MFMA GEMM: C[M][N] = A[M][K] * B[N][K]^T + bias ----------------
__global__ __launch_bounds__(256) void gemm_bt_k(const unsigned short* __restrict__ A,
                                                 const unsigned short* __restrict__ B,
                                                 void* __restrict__ Cv,
                                                 const float* __restrict__ bias1,
                                                 const float* __restrict__ bias2,
                                                 int M, int N, int K, int out_f16) {
    const int bn = blockIdx.x, bm = blockIdx.y;
    const int tid = threadIdx.x;
    const int wave = tid >> 6, lane = tid & 63;
    const int wm = (wave >> 1) * 64, wn = (wave & 1) * 64;

    __shared__ unsigned short As[128 * 64];
    __shared__ unsigned short Bs[128 * 64];

    f32x4 acc[4][4] = {};

    for (int k0 = 0; k0 < K; k0 += 64) {
#pragma unroll
        for (int i = 0; i < 4; ++i) {
            int bo = (tid + i * 256) * 16;
            int r = bo >> 7;
            int cb = bo & 127;
            *(uint4*)((char*)As + bo) =
                *(const uint4*)((const char*)(A + (size_t)(bm * 128 + r) * K + k0) + cb);
            *(uint4*)((char*)Bs + bo) =
                *(const uint4*)((const char*)(B + (size_t)(bn * 128 + r) * K + k0) + cb);
        }
        __syncthreads();
#pragma unroll
        for (int kk = 0; kk < 64; kk += 32) {
            int kb = kk + (lane >> 4) * 8;
            bf16x8 af[4], bfr[4];
#pragma unroll
            for (int mi = 0; mi < 4; ++mi)
                af[mi] = *(const bf16x8*)&As[(wm + mi * 16 + (lane & 15)) * 64 + kb];
#pragma unroll
            for (int ni = 0; ni < 4; ++ni)
                bfr[ni] = *(const bf16x8*)&Bs[(wn + ni * 16 + (lane & 15)) * 64 + kb];
#pragma unroll
            for (int mi = 0; mi < 4; ++mi)
#pragma unroll
                for (int ni = 0; ni < 4; ++ni)
                    acc[mi][ni] = __builtin_amdgcn_mfma_f32_16x16x32_bf16(
                        af[mi], bfr[ni], acc[mi][ni], 0, 0, 0);
        }
        __syncthreads();
    }

#pragma unroll
    for (int ni = 0; ni < 4; ++ni) {
        int col = bn * 128 + wn + ni * 16 + (lane & 15);
        float bv = bias1 ? bias1[col] : 0.0f;
        if (bias2) bv += bias2[col];
#pragma unroll
        for (int mi = 0; mi < 4; ++mi) {
            int row = bm * 128 + wm + mi * 16 + (lane >> 4) * 4;
#pragma unroll
            for (int r = 0; r < 4; ++r) {
                float v = acc[mi][ni][r] + bv;
                if (out_f16)
                    ((_Float16*)Cv)[(size_t)(row + r) * N + col] = (_Float16)v;
                else
                    ((float*)Cv)[(size_t)(row + r) * N + col] = v;
            }
        }
    }
}

// ---------------- persistent recurrent kernel ----------------
// Structure = round 5 (best measured: 5.45 ms) with two changes:
//  (a) DPP-ladder reduce instead of 24x shfl_xor (-140 cy/step),
//  (b) no per-step __syncthreads: intra-WG slice propagation is dataflow
//      via LDS tags (data ds_write -> lgkmcnt(0) -> tag ds_write; consumers
//      spin on the tag). Dots on already-staged slices overlap the global
//      straggler's poll. Slice order is compile-time 0..7 (runtime stagger
//      would runtime-index the AGPR weight array -> scratch, rule #20).
// Poll primitive unchanged from R5: single-outstanding dwordx4 + vmcnt(0)
// + s_sleep(1) per miss (R9/R10 lesson: deeper polling inflates LLC RTT).
// xg stays in the vmcnt domain, prefetched one step ahead (R9/R10 lesson:
// s_load xg shares lgkmcnt with LDS -> forced full drains in the dot loop).
__global__ __launch_bounds__(512, 2) void lstm_rec_k(const _Float16* __restrict__ Whh16,
                                                     const _Float16* __restrict__ xg,
                                                     unsigned* __restrict__ hs32) {
    const int tid = threadIdx.x;
    const int wave = tid >> 6;
    const int lane = tid & 63;
    const int unit = (blockIdx.x << 3) + wave;   // hidden unit owned by this wave

    __shared__ unsigned hpk[2][1024];            // packed f16 pairs of h_t (ping-pong)
    __shared__ unsigned ltag[16];                // per-slice arrival tags [buf][8]

    if (tid < 16) ltag[tid] = 0xFFFFFFFFu;

    // weights: W[g][k][p] = dword p of Whh16[g*H + unit][k*256 + lane*4 ..+3]
    unsigned W[4][8][2];
#pragma unroll
    for (int g = 0; g < 4; ++g) {
        const _Float16* wr = Whh16 + ((size_t)(g * HH) + unit) * HH + (lane << 2);
#pragma unroll
        for (int k = 0; k < 8; ++k) {
            u32x2 v = *(const u32x2*)(wr + (k << 8));
            W[g][k][0] = v.x; W[g][k][1] = v.y;
        }
    }
#pragma unroll
    for (int g = 0; g < 4; ++g)
#pragma unroll
        for (int k = 0; k < 8; ++k)
            asm volatile("" : "+a"(W[g][k][0]), "+a"(W[g][k][1]));

    __syncthreads();   // ltag init visible to all waves

    float creg = 0.0f;

    // xg prefetch pipeline: values for step t loaded during step t-1
    float xg0 = 0.f, xg1 = 0.f, xg2 = 0.f, xg3 = 0.f;
    if (lane == 0) {
        const _Float16* xr = xg + unit;
        xg0 = (float)xr[0]; xg1 = (float)xr[2048];
        xg2 = (float)xr[4096]; xg3 = (float)xr[6144];
    }

    for (int t = 0; t < TT; ++t) {
        const int buf = t & 1;
        const unsigned tu = (unsigned)t;

        // issue next step's xg loads early (hide HBM latency under this step)
        float nx0 = 0.f, nx1 = 0.f, nx2 = 0.f, nx3 = 0.f;
        if (lane == 0 && t + 1 < TT) {
            const _Float16* xr = xg + ((size_t)(t + 1) << 13) + unit;
            nx0 = (float)xr[0]; nx1 = (float)xr[2048];
            nx2 = (float)xr[4096]; nx3 = (float)xr[6144];
        }

        // poll own 256-word slice of h_t (single outstanding, LLC bypass)
        const unsigned* pp = hs32 + ((size_t)t << 11) + (wave << 8) + (lane << 2);
        uint4 hv;
        for (;;) {
            asm volatile(
                "global_load_dwordx4 %0, %1, off sc0 sc1\n\t"
                "s_waitcnt vmcnt(0)"
                : "=&v"(hv) : "v"(pp));
            int ok = (hv.x >> 16) == tu && (hv.y >> 16) == tu &&
                     (hv.z >> 16) == tu && (hv.w >> 16) == tu;
            if (__all(ok)) break;
            __builtin_amdgcn_s_sleep(1);
        }

        // stage packed f16 pairs to LDS; data -> lgkm drain -> tag publish
        unsigned plo = __builtin_amdgcn_perm(hv.y, hv.x, 0x05040100);
        unsigned phi = __builtin_amdgcn_perm(hv.w, hv.z, 0x05040100);
        {
            u32x2 pk; pk.x = plo; pk.y = phi;
            *(u32x2*)&hpk[buf][(wave << 7) + (lane << 1)] = pk;
            asm volatile("s_waitcnt lgkmcnt(0)" ::: "memory");
            if (lane == 0) ((volatile unsigned*)ltag)[(buf << 3) + wave] = tu;
        }

        // dots over 8 slices: own slice from regs, others gated by LDS tag
        float a0 = 0.f, a1 = 0.f, a2 = 0.f, a3 = 0.f;
#define DOTS(kk, PLO, PHI) do {                                               \
        f16x2 hlo = u2h(PLO), hhi = u2h(PHI);                                 \
        a0 = FDOT2(u2h(W[0][kk][0]), hlo, a0);                                \
        a0 = FDOT2(u2h(W[0][kk][1]), hhi, a0);                                \
        a1 = FDOT2(u2h(W[1][kk][0]), hlo, a1);                                \
        a1 = FDOT2(u2h(W[1][kk][1]), hhi, a1);                                \
        a2 = FDOT2(u2h(W[2][kk][0]), hlo, a2);                                \
        a2 = FDOT2(u2h(W[2][kk][1]), hhi, a2);                                \
        a3 = FDOT2(u2h(W[3][kk][0]), hlo, a3);                                \
        a3 = FDOT2(u2h(W[3][kk][1]), hhi, a3);                                \
    } while (0)
#define SLICE(kk) do {                                                        \
        if ((kk) == wave) {                                                   \
            DOTS(kk, plo, phi);                                               \
        } else {                                                              \
            while (((volatile unsigned*)ltag)[(buf << 3) + (kk)] != tu) {}    \
            asm volatile("" ::: "memory");                                    \
            __builtin_amdgcn_sched_barrier(0);                                \
            u32x2 hp = *(const u32x2*)&hpk[buf][((kk) << 7) + (lane << 1)];   \
            DOTS(kk, hp.x, hp.y);                                             \
        }                                                                     \
    } while (0)
        SLICE(0); SLICE(1); SLICE(2); SLICE(3);
        SLICE(4); SLICE(5); SLICE(6); SLICE(7);
#undef SLICE
#undef DOTS

        // wave reduce (DPP ladder) -> uniform sums
        float s0 = dpp_sum64(a0);
        float s1 = dpp_sum64(a1);
        float s2 = dpp_sum64(a2);
        float s3 = dpp_sum64(a3);

        if (lane == 0) {
            float gi = s0 + xg0;
            float gf = s1 + xg1;
            float gg = s2 + xg2;
            float go = s3 + xg3;
            float ei = __expf(-gi), ef = __expf(-gf), eo = __expf(-go);
            float eg = __expf(-2.0f * gg);
            float si = 1.0f / (1.0f + ei);
            float sf = 1.0f / (1.0f + ef);
            float so = 1.0f / (1.0f + eo);
            float tg = 2.0f / (1.0f + eg) - 1.0f;
            creg = sf * creg + si * tg;
            float ec = __expf(-2.0f * creg);
            float th = 2.0f / (1.0f + ec) - 1.0f;
            float h = so * th;
            _Float16 fh = (_Float16)h;
            unsigned word = ((tu + 1u) << 16) |
                            (unsigned)__builtin_bit_cast(unsigned short, fh);
            unsigned* hd = hs32 + (((size_t)(t + 1)) << 11) + unit;
            // fire-and-forget publish; retired by next step's poll vmcnt(0)
            asm volatile("global_store_dword %0, %1, off sc0 sc1"
                         :: "v"(hd), "v"(word));
        }
        // rotate xg pipeline
        xg0 = nx0; xg1 = nx1; xg2 = nx2; xg3 = nx3;
    }
}

// ---------------- log-softmax over rows of [T][TAGS] ----------------
__global__ __launch_bounds__(256) void lsm_k(const float* __restrict__ tag,
                                             float* __restrict__ out) {
    const int row = blockIdx.x, tid = threadIdx.x;
    const int wave = tid >> 6, lane = tid & 63;
    const float* p = tag + ((size_t)row << 10);
    float v0 = p[tid], v1 = p[tid + 256], v2 = p[tid + 512], v3 = p[tid + 768];
    float m = fmaxf(fmaxf(v0, v1), fmaxf(v2, v3));
#pragma unroll
    for (int off = 32; off >= 1; off >>= 1) m = fmaxf(m, __shfl_xor(m, off, 64));
    __shared__ float redm[4];
    __shared__ float reds[4];
    if (lane == 0) redm[wave] = m;
    __syncthreads();
    m = fmaxf(fmaxf(redm[0], redm[1]), fmaxf(redm[2], redm[3]));
    float s = __expf(v0 - m) + __expf(v1 - m) + __expf(v2 - m) + __expf(v3 - m);
#pragma unroll
    for (int off = 32; off >= 1; off >>= 1) s += __shfl_xor(s, off, 64);
    if (lane == 0) reds[wave] = s;
    __syncthreads();
    s = reds[0] + reds[1] + reds[2] + reds[3];
    float lse = m + __logf(s);
    float* o = out + ((size_t)row << 10);
    o[tid] = v0 - lse; o[tid + 256] = v1 - lse;
    o[tid + 512] = v2 - lse; o[tid + 768] = v3 - lse;
}

extern "C" void kernel_launch(void* const* d_in, const int* in_sizes, int n_in,
                              void* d_out, int out_size, void* d_ws, size_t ws_size,
                              hipStream_t stream) {
    const float* x    = (const float*)d_in[0];
    const float* Wih  = (const float*)d_in[1];
    const float* Whh  = (const float*)d_in[2];
    const float* bih  = (const float*)d_in[3];
    const float* bhh  = (const float*)d_in[4];
    const float* Wout = (const float*)d_in[5];
    const float* bout = (const float*)d_in[6];
    float* out = (float*)d_out;

    // workspace carve with time-sliced aliasing (all uses stream-ordered):
    //  A: hs32 [16.8MB] tagged h words; aliased by `tag` in phase C
    //  B: xg   [32MB]   f16 gate preacts
    //  C: 33.6MB region:
    //     pre-GEMM-A: xbf @C+0 (4MB), wihbf @C+4MB (16MB)
    //     pre-rec   : Whh16 @C+0 (33.6MB)   [cvt AFTER phase A]
    //     post-rec  : woutbf @C+0 (4MB), hs bf16 @C+4MB (8MB)
    char* ws = (char*)d_ws;
    size_t off = 0;
    unsigned* hs32 = (unsigned*)(ws + off); off += (size_t)(TT + 1) * HH * 4;   // 16.8MB
    float* tag = (float*)hs32;                                                   // alias
    _Float16* xg = (_Float16*)(ws + off); off += (size_t)TT * G4 * 2;            // 32MB
    char* C = ws + off; off += (size_t)G4 * HH * 2;                              // 33.6MB
    unsigned short* xbf    = (unsigned short*)(C);
    unsigned short* wihbf  = (unsigned short*)(C + ((size_t)TT * DD * 2) * 2);   // C+4MB
    _Float16* Whh16        = (_Float16*)(C);
    unsigned short* woutbf = (unsigned short*)(C);
    unsigned short* hs     = (unsigned short*)(C + (size_t)4 * 1024 * 1024);     // C+4MB

    // clear ALL tags every call (h_0 = tag 0 + f16 zero; also prevents timed
    // replays from observing stale tags)
    hipMemsetAsync(hs32, 0, (size_t)(TT + 1) * HH * 4, stream);

    // converts for phase A
    cvt_bf16_k<<<(TT * DD) / 1024, 256, 0, stream>>>(x, xbf, TT * DD);
    cvt_bf16_k<<<(G4 * DD) / 1024, 256, 0, stream>>>(Wih, wihbf, G4 * DD);

    // phase A: xg[T][4H] (f16) = x @ W_ih^T + (b_ih + b_hh)
    gemm_bt_k<<<dim3(G4 / 128, TT / 128), 256, 0, stream>>>(xbf, wihbf, (void*)xg,
                                                            bih, bhh, TT, G4, DD, 1);

    // W_hh -> f16 (overwrites xbf/wihbf region — phase A is done with them)
    cvt_f16_k<<<(G4 * HH) / 1024, 256, 0, stream>>>(Whh, Whh16, G4 * HH);

    // phase B: recurrence (persistent dataflow kernel, 1 WG/CU)
    {
        const _Float16* whh_p = Whh16;
        const _Float16* xg_p = xg;
        unsigned* hs32_p = hs32;
        void* args[] = {(void*)&whh_p, (void*)&xg_p, (void*)&hs32_p};
        hipLaunchCooperativeKernel((const void*)lstm_rec_k, dim3(256), dim3(512), args, 0,
                                   stream);
    }

    // converts for phase C (overwrite Whh16 region — recurrence is done)
    cvt_bf16_k<<<(TAGS_ * HH) / 1024, 256, 0, stream>>>(Wout, woutbf, TAGS_ * HH);
    cvt_lo16f_k<<<(TT * HH) / 1024, 256, 0, stream>>>(hs32 + HH, hs, TT * HH);

    // phase C: tag[T][TAGS] = hs @ W_out^T + b_out  (tag aliases hs32; the
    // post-pass above already consumed hs32)
    gemm_bt_k<<<dim3(TAGS_ / 128, TT / 128), 256, 0, stream>>>(hs, woutbf, (void*)tag,
                                                               bout, nullptr,
                                                               TT, TAGS_, HH, 0);

    // log-softmax
    lsm_k<<<TT, 256, 0, stream>>>(tag, out);
}